// Round 1
// baseline (137.733 us; speedup 1.0000x reference)
//
#include <hip/hip_runtime.h>
#include <math.h>

#define NPTS 16384
#define NB   32
#define NA   4
#define NC   256
#define KNN  32
#define NROW 128   // NB*NA

// workspace layout (float offsets)
#define OFF_LF        0        // 128*256
#define OFF_QKV       32768    // 128*768
#define OFF_POSLIN    131072   // 128*256
#define OFF_POSSTATS  163840   // 256 sum + 256 sumsq
#define OFF_GLIN      164352   // 128*256
#define OFF_GSTATS    197120   // 512
#define OFF_AV        197632   // 128*256
#define OFF_RESLIN    230400   // 128*256
#define OFF_RESSTATS  263168   // 512  (atomic, memset each call)
#define OFF_PROBSTATS 263680   // 9 sum + 9 sumsq (atomic), padded to 32
#define OFF_PROBLIN   263712   // 128*9
// total = 264864 floats ~= 1.06 MB

// ---------------- K1: knn + gather + maxpool ----------------
__global__ __launch_bounds__(256) void knn_kernel(
    const float* __restrict__ a_points, const float* __restrict__ sa_xyz,
    const float* __restrict__ sa_x, float* __restrict__ lf) {
  const int blk = blockIdx.x;        // b*4 + a
  const int b   = blk >> 2;
  const int t   = threadIdx.x;
  const float ax = a_points[blk*3 + 0];
  const float ay = a_points[blk*3 + 1];
  const float az = a_points[blk*3 + 2];
  const float* __restrict__ xyz = sa_xyz + (size_t)b * NPTS * 3;

  // 64 distances per thread, registers only (static indexing everywhere)
  float d[64];
#pragma unroll
  for (int j = 0; j < 64; ++j) {
    const int n = t + 256*j;
    const float dx = xyz[n*3+0] - ax;
    const float dy = xyz[n*3+1] - ay;
    const float dz = xyz[n*3+2] - az;
    d[j] = dx*dx + dy*dy + dz*dz;
  }
  float mv = d[0]; int mj = 0;
#pragma unroll
  for (int j = 1; j < 64; ++j) { if (d[j] < mv) { mv = d[j]; mj = j; } }
  int mi = t + 256*mj;

  __shared__ float s_wv[4];
  __shared__ int   s_wi[4];
  __shared__ int   s_win;
  __shared__ int   s_top[KNN];
  const int lane = t & 63, w = t >> 6;

  for (int r = 0; r < KNN; ++r) {
    // wave butterfly argmin with (value, index) tie-break (smaller index wins)
    float v = mv; int i = mi;
#pragma unroll
    for (int off = 1; off < 64; off <<= 1) {
      const float ov = __shfl_xor(v, off);
      const int   oi = __shfl_xor(i, off);
      if (ov < v || (ov == v && oi < i)) { v = ov; i = oi; }
    }
    if (lane == 0) { s_wv[w] = v; s_wi[w] = i; }
    __syncthreads();
    if (t == 0) {
      float bv = s_wv[0]; int bi = s_wi[0];
#pragma unroll
      for (int w2 = 1; w2 < 4; ++w2)
        if (s_wv[w2] < bv || (s_wv[w2] == bv && s_wi[w2] < bi)) { bv = s_wv[w2]; bi = s_wi[w2]; }
      s_top[r] = bi; s_win = bi;
    }
    __syncthreads();
    const int wi = s_win;
    if ((wi & 255) == t) {          // I own the extracted element
      const int kj = wi >> 8;
#pragma unroll
      for (int j = 0; j < 64; ++j) if (j == kj) d[j] = 3.0e38f;
      mv = d[0]; mj = 0;
#pragma unroll
      for (int j = 1; j < 64; ++j) { if (d[j] < mv) { mv = d[j]; mj = j; } }
      mi = t + 256*mj;
    }
  }
  __syncthreads();

  // gather 32 rows of sa_x, maxpool per channel (coalesced 1KB row reads)
  const float* __restrict__ xb = sa_x + (size_t)b * NPTS * NC;
  float acc = -3.0e38f;
  for (int r = 0; r < KNN; ++r) {
    const int n = s_top[r];
    acc = fmaxf(acc, xb[(size_t)n * NC + t]);
  }
  lf[(size_t)blk * NC + t] = acc;
}

// ---------------- K2: qkv GEMM + pos/gfeat linears + their stats ----------------
__global__ __launch_bounds__(256) void lin1_kernel(
    const float* __restrict__ lf, const float* __restrict__ qkv_W,
    const float* __restrict__ a_points,
    const float* __restrict__ pos_W, const float* __restrict__ pos_b,
    const float* __restrict__ g_W,
    float* __restrict__ qkv, float* __restrict__ pos_lin, float* __restrict__ pos_stats,
    float* __restrict__ g_lin, float* __restrict__ g_stats) {
  const int blk = blockIdx.x;
  if (blk < 96) {
    // qkv: 8 rowtiles(16) x 12 otiles(64); thread = (ot 0..63, rt 0..3), 4 rows each
    const int r0 = (blk / 12) * 16;
    const int o0 = (blk % 12) * 64;
    const int ot = threadIdx.x & 63;
    const int rt = threadIdx.x >> 6;
    const int o  = o0 + ot;
    const float* __restrict__ wrow = qkv_W + (size_t)o * NC;
    const float* __restrict__ l0p  = lf + (size_t)(r0 + rt*4) * NC;
    float acc0 = 0.f, acc1 = 0.f, acc2 = 0.f, acc3 = 0.f;
    for (int c = 0; c < NC; c += 4) {
      const float4 w4 = *(const float4*)(wrow + c);
      const float4 l0 = *(const float4*)(l0p + c);
      const float4 l1 = *(const float4*)(l0p + NC + c);
      const float4 l2 = *(const float4*)(l0p + 2*NC + c);
      const float4 l3 = *(const float4*)(l0p + 3*NC + c);
      acc0 = fmaf(l0.x,w4.x,acc0); acc0 = fmaf(l0.y,w4.y,acc0); acc0 = fmaf(l0.z,w4.z,acc0); acc0 = fmaf(l0.w,w4.w,acc0);
      acc1 = fmaf(l1.x,w4.x,acc1); acc1 = fmaf(l1.y,w4.y,acc1); acc1 = fmaf(l1.z,w4.z,acc1); acc1 = fmaf(l1.w,w4.w,acc1);
      acc2 = fmaf(l2.x,w4.x,acc2); acc2 = fmaf(l2.y,w4.y,acc2); acc2 = fmaf(l2.z,w4.z,acc2); acc2 = fmaf(l2.w,w4.w,acc2);
      acc3 = fmaf(l3.x,w4.x,acc3); acc3 = fmaf(l3.y,w4.y,acc3); acc3 = fmaf(l3.z,w4.z,acc3); acc3 = fmaf(l3.w,w4.w,acc3);
    }
    const int r = r0 + rt*4;
    qkv[(size_t)(r+0)*768 + o] = acc0;
    qkv[(size_t)(r+1)*768 + o] = acc1;
    qkv[(size_t)(r+2)*768 + o] = acc2;
    qkv[(size_t)(r+3)*768 + o] = acc3;
  } else if (blk == 96) {
    // pos_lin = (a_points - mean_a) @ pos_W^T + pos_b ; channel stats
    const int c = threadIdx.x;
    const float w0 = pos_W[c*3+0], w1 = pos_W[c*3+1], w2 = pos_W[c*3+2];
    const float bb = pos_b[c];
    float sum = 0.f, sumsq = 0.f;
    for (int b = 0; b < NB; ++b) {
      float gx=0.f, gy=0.f, gz=0.f;
      for (int a = 0; a < NA; ++a) {
        gx += a_points[(b*NA+a)*3+0];
        gy += a_points[(b*NA+a)*3+1];
        gz += a_points[(b*NA+a)*3+2];
      }
      gx *= 0.25f; gy *= 0.25f; gz *= 0.25f;
      for (int a = 0; a < NA; ++a) {
        const float rx = a_points[(b*NA+a)*3+0] - gx;
        const float ry = a_points[(b*NA+a)*3+1] - gy;
        const float rz = a_points[(b*NA+a)*3+2] - gz;
        const float v = rx*w0 + ry*w1 + rz*w2 + bb;
        pos_lin[(b*NA+a)*NC + c] = v;
        sum += v; sumsq += v*v;
      }
    }
    pos_stats[c] = sum; pos_stats[NC + c] = sumsq;
  } else {
    // gfeat_lin = a_points @ g_W^T (no bias) ; channel stats
    const int c = threadIdx.x;
    const float w0 = g_W[c*3+0], w1 = g_W[c*3+1], w2 = g_W[c*3+2];
    float sum = 0.f, sumsq = 0.f;
    for (int b = 0; b < NB; ++b) {
      for (int a = 0; a < NA; ++a) {
        const float px = a_points[(b*NA+a)*3+0];
        const float py = a_points[(b*NA+a)*3+1];
        const float pz = a_points[(b*NA+a)*3+2];
        const float v = px*w0 + py*w1 + pz*w2;
        g_lin[(b*NA+a)*NC + c] = v;
        sum += v; sumsq += v*v;
      }
    }
    g_stats[c] = sum; g_stats[NC + c] = sumsq;
  }
}

// ---------------- K3: attention (one block per batch, wave = head) ----------------
__global__ __launch_bounds__(256) void attn_kernel(
    const float* __restrict__ qkv, const float* __restrict__ pos_lin,
    const float* __restrict__ pos_stats,
    const float* __restrict__ pos_gamma, const float* __restrict__ pos_beta,
    float* __restrict__ av) {
  const int b    = blockIdx.x;
  const int lane = threadIdx.x & 63;
  const int h    = threadIdx.x >> 6;
  const int c    = h*64 + lane;
  const float mean = pos_stats[c] * (1.0f/NROW);
  const float var  = pos_stats[NC + c] * (1.0f/NROW) - mean*mean;
  const float rstd = 1.0f / sqrtf(var + 1e-5f);
  const float ga = pos_gamma[c], be = pos_beta[c];
  float q[4], k[4], v[4];
#pragma unroll
  for (int m = 0; m < 4; ++m) {
    const int row = b*NA + m;
    const float p = ga * (pos_lin[row*NC + c] - mean) * rstd + be;
    q[m] = qkv[(size_t)row*768 +       c] + p;
    k[m] = qkv[(size_t)row*768 + 256 + c] + p;
    v[m] = qkv[(size_t)row*768 + 512 + c] + p;
  }
  float s[4][4];
#pragma unroll
  for (int m = 0; m < 4; ++m) {
#pragma unroll
    for (int n = 0; n < 4; ++n) {
      float p = q[m]*k[n];
#pragma unroll
      for (int off = 1; off < 64; off <<= 1) p += __shfl_xor(p, off);
      s[m][n] = p * 0.125f;   // 1/sqrt(64)
    }
  }
#pragma unroll
  for (int m = 0; m < 4; ++m) {
    const float mx = fmaxf(fmaxf(s[m][0], s[m][1]), fmaxf(s[m][2], s[m][3]));
    const float e0 = expf(s[m][0]-mx), e1 = expf(s[m][1]-mx);
    const float e2 = expf(s[m][2]-mx), e3 = expf(s[m][3]-mx);
    const float inv = 1.0f / (e0+e1+e2+e3);
    const float o = (e0*v[0] + e1*v[1] + e2*v[2] + e3*v[3]) * inv;
    av[(size_t)(b*NA+m)*NC + c] = o;
  }
}

// ---------------- K4: res GEMM + bias + atomic channel stats ----------------
__global__ __launch_bounds__(256) void res_kernel(
    const float* __restrict__ av, const float* __restrict__ res_W,
    const float* __restrict__ res_b,
    float* __restrict__ res_lin, float* __restrict__ res_stats) {
  const int blk = blockIdx.x;         // 8 rowtiles x 4 otiles
  const int r0 = (blk >> 2) * 16;
  const int o0 = (blk & 3) * 64;
  const int ot = threadIdx.x & 63;
  const int rt = threadIdx.x >> 6;
  const int o  = o0 + ot;
  const float* __restrict__ wrow = res_W + (size_t)o * NC;
  const float* __restrict__ ap   = av + (size_t)(r0 + rt*4) * NC;
  float acc0=0.f, acc1=0.f, acc2=0.f, acc3=0.f;
  for (int c = 0; c < NC; c += 4) {
    const float4 w4 = *(const float4*)(wrow + c);
    const float4 l0 = *(const float4*)(ap + c);
    const float4 l1 = *(const float4*)(ap + NC + c);
    const float4 l2 = *(const float4*)(ap + 2*NC + c);
    const float4 l3 = *(const float4*)(ap + 3*NC + c);
    acc0 = fmaf(l0.x,w4.x,acc0); acc0 = fmaf(l0.y,w4.y,acc0); acc0 = fmaf(l0.z,w4.z,acc0); acc0 = fmaf(l0.w,w4.w,acc0);
    acc1 = fmaf(l1.x,w4.x,acc1); acc1 = fmaf(l1.y,w4.y,acc1); acc1 = fmaf(l1.z,w4.z,acc1); acc1 = fmaf(l1.w,w4.w,acc1);
    acc2 = fmaf(l2.x,w4.x,acc2); acc2 = fmaf(l2.y,w4.y,acc2); acc2 = fmaf(l2.z,w4.z,acc2); acc2 = fmaf(l2.w,w4.w,acc2);
    acc3 = fmaf(l3.x,w4.x,acc3); acc3 = fmaf(l3.y,w4.y,acc3); acc3 = fmaf(l3.z,w4.z,acc3); acc3 = fmaf(l3.w,w4.w,acc3);
  }
  const float bias = res_b[o];
  acc0 += bias; acc1 += bias; acc2 += bias; acc3 += bias;
  const int r = r0 + rt*4;
  res_lin[(size_t)(r+0)*NC + o] = acc0;
  res_lin[(size_t)(r+1)*NC + o] = acc1;
  res_lin[(size_t)(r+2)*NC + o] = acc2;
  res_lin[(size_t)(r+3)*NC + o] = acc3;
  atomicAdd(&res_stats[o],      acc0+acc1+acc2+acc3);
  atomicAdd(&res_stats[NC + o], acc0*acc0 + acc1*acc1 + acc2*acc2 + acc3*acc3);
}

// ---------------- K5: res BN + add, g BN + max, concat, prob GEMM + stats ----------------
__global__ __launch_bounds__(256) void final_kernel(
    const float* __restrict__ lf, const float* __restrict__ res_lin,
    const float* __restrict__ res_stats,
    const float* __restrict__ res_gamma, const float* __restrict__ res_beta,
    const float* __restrict__ g_lin, const float* __restrict__ g_stats,
    const float* __restrict__ g_gamma, const float* __restrict__ g_beta,
    const float* __restrict__ prob_W,
    float* __restrict__ prob_lin, float* __restrict__ prob_stats) {
  const int b = blockIdx.x;
  const int c = threadIdx.x;
  __shared__ float s_feat[NA][2*NC];
  const float rmean = res_stats[c] * (1.0f/NROW);
  const float rvar  = res_stats[NC+c] * (1.0f/NROW) - rmean*rmean;
  const float rrstd = 1.0f / sqrtf(rvar + 1e-5f);
  const float rg = res_gamma[c], rb = res_beta[c];
  const float gmean = g_stats[c] * (1.0f/NROW);
  const float gvar  = g_stats[NC+c] * (1.0f/NROW) - gmean*gmean;
  const float grstd = 1.0f / sqrtf(gvar + 1e-5f);
  const float gg = g_gamma[c], gb = g_beta[c];
  float gm = -3.0e38f;
#pragma unroll
  for (int a = 0; a < NA; ++a) {
    const int row = b*NA + a;
    const float resv = rg * (res_lin[(size_t)row*NC + c] - rmean) * rrstd + rb;
    s_feat[a][c] = lf[(size_t)row*NC + c] + resv;
    const float gv = gg * (g_lin[(size_t)row*NC + c] - gmean) * grstd + gb;
    gm = fmaxf(gm, gv);
  }
#pragma unroll
  for (int a = 0; a < NA; ++a) s_feat[a][NC + c] = gm;
  __syncthreads();
  const int m    = c >> 6;    // wave -> anchor row
  const int lane = c & 63;
  for (int j = 0; j < 9; ++j) {
    float p = 0.f;
#pragma unroll
    for (int k2 = 0; k2 < 8; ++k2) {
      const int cc = lane + 64*k2;
      p = fmaf(s_feat[m][cc], prob_W[j*2*NC + cc], p);
    }
#pragma unroll
    for (int off = 1; off < 64; off <<= 1) p += __shfl_xor(p, off);
    if (lane == 0) {
      prob_lin[(b*NA+m)*9 + j] = p;
      atomicAdd(&prob_stats[j],   p);
      atomicAdd(&prob_stats[9+j], p*p);
    }
  }
}

// ---------------- K6: prob BN -> out ----------------
__global__ __launch_bounds__(256) void out_kernel(
    const float* __restrict__ prob_lin, const float* __restrict__ prob_stats,
    const float* __restrict__ prob_gamma, const float* __restrict__ prob_beta,
    float* __restrict__ out) {
  const int i = blockIdx.x*256 + threadIdx.x;
  if (i >= NROW*9) return;
  const int j = i % 9;
  const float mean = prob_stats[j] * (1.0f/NROW);
  const float var  = prob_stats[9+j] * (1.0f/NROW) - mean*mean;
  const float rstd = 1.0f / sqrtf(var + 1e-5f);
  out[i] = prob_gamma[j] * (prob_lin[i] - mean) * rstd + prob_beta[j];
}

extern "C" void kernel_launch(void* const* d_in, const int* in_sizes, int n_in,
                              void* d_out, int out_size, void* d_ws, size_t ws_size,
                              hipStream_t stream) {
  const float* a_points  = (const float*)d_in[0];
  const float* sa_x      = (const float*)d_in[1];
  const float* sa_xyz    = (const float*)d_in[2];
  // d_in[3] xyz_raw: unused by the reference
  const float* g_W       = (const float*)d_in[4];
  const float* g_gamma   = (const float*)d_in[5];
  const float* g_beta    = (const float*)d_in[6];
  const float* qkv_W     = (const float*)d_in[7];
  const float* pos_W     = (const float*)d_in[8];
  const float* pos_b     = (const float*)d_in[9];
  const float* pos_gamma = (const float*)d_in[10];
  const float* pos_beta  = (const float*)d_in[11];
  const float* res_W     = (const float*)d_in[12];
  const float* res_b     = (const float*)d_in[13];
  const float* res_gamma = (const float*)d_in[14];
  const float* res_beta  = (const float*)d_in[15];
  const float* prob_W    = (const float*)d_in[16];
  const float* prob_gamma= (const float*)d_in[17];
  const float* prob_beta = (const float*)d_in[18];
  float* ws  = (float*)d_ws;
  float* out = (float*)d_out;

  // zero the atomic-stat region every call (ws is not re-poisoned between replays)
  hipMemsetAsync(ws + OFF_RESSTATS, 0, (512 + 32) * sizeof(float), stream);

  knn_kernel<<<128, 256, 0, stream>>>(a_points, sa_xyz, sa_x, ws + OFF_LF);
  lin1_kernel<<<98, 256, 0, stream>>>(ws + OFF_LF, qkv_W, a_points, pos_W, pos_b, g_W,
      ws + OFF_QKV, ws + OFF_POSLIN, ws + OFF_POSSTATS, ws + OFF_GLIN, ws + OFF_GSTATS);
  attn_kernel<<<32, 256, 0, stream>>>(ws + OFF_QKV, ws + OFF_POSLIN, ws + OFF_POSSTATS,
      pos_gamma, pos_beta, ws + OFF_AV);
  res_kernel<<<32, 256, 0, stream>>>(ws + OFF_AV, res_W, res_b,
      ws + OFF_RESLIN, ws + OFF_RESSTATS);
  final_kernel<<<32, 256, 0, stream>>>(ws + OFF_LF, ws + OFF_RESLIN, ws + OFF_RESSTATS,
      res_gamma, res_beta, ws + OFF_GLIN, ws + OFF_GSTATS, g_gamma, g_beta, prob_W,
      ws + OFF_PROBLIN, ws + OFF_PROBSTATS);
  out_kernel<<<5, 256, 0, stream>>>(ws + OFF_PROBLIN, ws + OFF_PROBSTATS,
      prob_gamma, prob_beta, out);
}